// Round 4
// baseline (2110.364 us; speedup 1.0000x reference)
//
#include <hip/hip_runtime.h>
#include <hip/hip_bf16.h>
#include <stdint.h>

#define B_DIM 8192
#define K_DIM 2048
#define N_DIM 2048
#define NSEG 4
#define NT (K_DIM / 32)   // 64 K-tiles of BK=32

typedef short bf16x8 __attribute__((ext_vector_type(8)));   // 8 bf16 (4 VGPRs)
typedef float f32x4 __attribute__((ext_vector_type(4)));
typedef unsigned short ushort8v __attribute__((ext_vector_type(8)));

typedef const __attribute__((address_space(1))) void* gas_ptr;
typedef __attribute__((address_space(3))) void* lds_ptr;

__device__ __forceinline__ unsigned short f2bf(float f) {
  uint32_t u = __float_as_uint(f);
  u += 0x7FFFu + ((u >> 16) & 1u);   // round-to-nearest-even
  return (unsigned short)(u >> 16);
}

// ---------------- W: f32 -> bf16 conversion, 8 elems/thread ----------------
__global__ __launch_bounds__(256)
void convert_kernel(const float* __restrict__ in, unsigned short* __restrict__ out, int n8) {
  int i = blockIdx.x * blockDim.x + threadIdx.x;
  const int stride = gridDim.x * blockDim.x;
  for (; i < n8; i += stride) {
    const float4* p = (const float4*)(in + (size_t)i * 8);
    float4 v0 = p[0];
    float4 v1 = p[1];
    ushort8v r;
    r[0] = f2bf(v0.x); r[1] = f2bf(v0.y); r[2] = f2bf(v0.z); r[3] = f2bf(v0.w);
    r[4] = f2bf(v1.x); r[5] = f2bf(v1.y); r[6] = f2bf(v1.z); r[7] = f2bf(v1.w);
    *(ushort8v*)(out + (size_t)i * 8) = r;
  }
}

// ------ fused: x f32 -> bf16 convert + gates = sigmoid(x @ Wg^T + bg) ------
__global__ __launch_bounds__(256)
void xconv_gates_kernel(const float* __restrict__ x, const float* __restrict__ Wg,
                        const float* __restrict__ bg,
                        unsigned short* __restrict__ xb, float* __restrict__ gates) {
  const int b = blockIdx.x;
  const int tid = threadIdx.x;
  const size_t base = (size_t)b * K_DIM + tid * 8;
  const float4 v0 = *(const float4*)(x + base);
  const float4 v1 = *(const float4*)(x + base + 4);
  ushort8v r;
  r[0] = f2bf(v0.x); r[1] = f2bf(v0.y); r[2] = f2bf(v0.z); r[3] = f2bf(v0.w);
  r[4] = f2bf(v1.x); r[5] = f2bf(v1.y); r[6] = f2bf(v1.z); r[7] = f2bf(v1.w);
  *(ushort8v*)(xb + base) = r;

  float a[4];
#pragma unroll
  for (int s = 0; s < 4; ++s) {
    const float4 w0 = *(const float4*)(Wg + (size_t)s * K_DIM + tid * 8);
    const float4 w1 = *(const float4*)(Wg + (size_t)s * K_DIM + tid * 8 + 4);
    a[s] = v0.x * w0.x + v0.y * w0.y + v0.z * w0.z + v0.w * w0.w
         + v1.x * w1.x + v1.y * w1.y + v1.z * w1.z + v1.w * w1.w;
  }
#pragma unroll
  for (int off = 1; off < 64; off <<= 1) {
#pragma unroll
    for (int s = 0; s < 4; ++s) a[s] += __shfl_xor(a[s], off);
  }
  __shared__ float red[4][4];
  const int wv = tid >> 6;
  if ((tid & 63) == 0) {
#pragma unroll
    for (int s = 0; s < 4; ++s) red[wv][s] = a[s];
  }
  __syncthreads();
  if (tid < 4) {
    float v = red[0][tid] + red[1][tid] + red[2][tid] + red[3][tid] + bg[tid];
    gates[(size_t)b * 4 + tid] = 1.f / (1.f + __expf(-v));
  }
}

// ------------- fused 4-segment GEMM, 16x16x32 MFMA, BK=32, 2 blocks/CU ------
// Block: 256 batch rows x 64 d-cols x 4 segs (eff 256x256). 8 waves = 2M x 4N:
// wave (wm,wn) owns rows wm*128..+128, d-cols wn*16..+16, ALL 4 segs in-lane.
// BK=32 -> one 16x16x32 MFMA consumes the whole K-tile: per tile per wave
// 32 MFMA (2 phases x 16) + 12 ds_read_b128 + 4 global_load_lds.
// LDS 64 KiB total (A dbuf 2x16K + B dbuf 2x16K) -> 2 blocks/CU: cross-block
// wave overlap hides the per-phase barrier/lgkm stalls (the R2 42% ceiling).
// Pipeline: A staged 1-tile-ahead (phase 0), B 2-ahead (phase 1, same-parity
// buffer is dead after phase 0's B-reads + barrier). Tile end: vmcnt(2)
// (A(t+1),B(t+1) done; B(t+2) stays in flight), vmcnt(0) only at t=NT-2.
__global__ __launch_bounds__(512, 4)
void seg_gemm_kernel(const unsigned short* __restrict__ Xb,
                     const unsigned short* __restrict__ Wb,
                     const float* __restrict__ b_seg,
                     const float* __restrict__ thr,
                     const float* __restrict__ gates,
                     float* __restrict__ out) {
  __shared__ __align__(128) char smem[65536];

  const int tid = threadIdx.x;
  const int lane = tid & 63;
  const int wid = tid >> 6;
  const int wm = wid >> 2;        // 0..1 (m half)
  const int wn = wid & 3;         // 0..3 (d quarter)

  // bijective XCD swizzle: 1024 blocks, 8 XCDs, 128 per XCD
  const int id = blockIdx.x;
  const int swz = (id & 7) * 128 + (id >> 3);
  const int m0 = (swz >> 5) * 256;
  const int n0 = (swz & 31) * 64;

  // ---- staging constants: dest linear L = tid*16 in an 8KB half-region ----
  // row = tid>>2 (64B rows), slot = tid&3; source pre-swizzled so that LDS
  // slot x of row r holds global k-bytes x*16 ^ ((r&8)<<2)  (involution).
  const int row_st = tid >> 2;                                      // 0..127
  const int ke_st  = ((((tid & 3) << 4) ^ (((tid >> 5) & 1) << 5)) >> 1);
  const int ldsd   = tid * 16;

  // ---- read constants (verified zero-conflict in R2) ----
  const int l15 = lane & 15;
  const int kg  = lane >> 4;       // 0..3
  const int aRd = l15 * 64 + ((kg * 16) ^ ((l15 & 8) << 2));
  const int wnB = wn * 1024;       // wn*16 rows * 64B

  f32x4 acc[NSEG][8];
#pragma unroll
  for (int s = 0; s < NSEG; ++s)
#pragma unroll
    for (int f = 0; f < 8; ++f) acc[s][f] = (f32x4){0.f, 0.f, 0.f, 0.f};

#define STAGE_A(t_) do { int par_ = (t_) & 1;                                       \
    const unsigned short* s0_ = Xb + (size_t)(m0 + row_st) * K_DIM + (t_) * 32 + ke_st; \
    __builtin_amdgcn_global_load_lds((gas_ptr)s0_, (lds_ptr)(smem + par_ * 16384 + ldsd), 16, 0, 0); \
    const unsigned short* s1_ = Xb + (size_t)(m0 + 128 + row_st) * K_DIM + (t_) * 32 + ke_st; \
    __builtin_amdgcn_global_load_lds((gas_ptr)s1_, (lds_ptr)(smem + par_ * 16384 + ldsd + 8192), 16, 0, 0); \
  } while (0)

#define STAGE_B(t_) do { int par_ = (t_) & 1;                                       \
    const unsigned short* s0_ = Wb + (size_t)(row_st >> 6) * (N_DIM * K_DIM) + (size_t)(n0 + (row_st & 63)) * K_DIM + (t_) * 32 + ke_st; \
    __builtin_amdgcn_global_load_lds((gas_ptr)s0_, (lds_ptr)(smem + 32768 + par_ * 16384 + ldsd), 16, 0, 0); \
    const unsigned short* s1_ = Wb + (size_t)((row_st + 128) >> 6) * (N_DIM * K_DIM) + (size_t)(n0 + (row_st & 63)) * K_DIM + (t_) * 32 + ke_st; \
    __builtin_amdgcn_global_load_lds((gas_ptr)s1_, (lds_ptr)(smem + 32768 + par_ * 16384 + ldsd + 8192), 16, 0, 0); \
  } while (0)

#define MFMA16(a_, b_, c_) __builtin_amdgcn_mfma_f32_16x16x32_bf16(a_, b_, c_, 0, 0, 0)

#define PHASE_MFMA(f0_) do {                                                        \
    __builtin_amdgcn_s_setprio(1);                                                  \
    _Pragma("unroll")                                                               \
    for (int ff = 0; ff < 4; ++ff) {                                                \
      acc[0][(f0_) + ff] = MFMA16(af[ff], bfr[0], acc[0][(f0_) + ff]);              \
      acc[1][(f0_) + ff] = MFMA16(af[ff], bfr[1], acc[1][(f0_) + ff]);              \
      acc[2][(f0_) + ff] = MFMA16(af[ff], bfr[2], acc[2][(f0_) + ff]);              \
      acc[3][(f0_) + ff] = MFMA16(af[ff], bfr[3], acc[3][(f0_) + ff]);              \
    }                                                                               \
    __builtin_amdgcn_s_setprio(0);                                                  \
  } while (0)

  // ---- prologue: A(0), B(0), B(1); keep B(1) in flight ----
  STAGE_A(0); STAGE_B(0); STAGE_B(1);
  asm volatile("s_waitcnt vmcnt(2)" ::: "memory");
  asm volatile("s_barrier" ::: "memory");

  bf16x8 bfr[NSEG];
  bf16x8 af[4];

  for (int t = 0; t < NT; ++t) {
    const char* Ab = smem + (t & 1) * 16384 + wm * 8192;
    const char* Bb = smem + 32768 + (t & 1) * 16384;

    // ---- phase 0: B frags + A frags f0..3; stage A(t+1) ----
#pragma unroll
    for (int s = 0; s < NSEG; ++s) bfr[s] = *(const bf16x8*)(Bb + s * 4096 + wnB + aRd);
#pragma unroll
    for (int ff = 0; ff < 4; ++ff) af[ff] = *(const bf16x8*)(Ab + ff * 1024 + aRd);
    if (t + 1 < NT) STAGE_A(t + 1);
    asm volatile("s_barrier" ::: "memory");
    asm volatile("s_waitcnt lgkmcnt(0)" ::: "memory");
    PHASE_MFMA(0);
    asm volatile("s_barrier" ::: "memory");

    // ---- phase 1: A frags f4..7; stage B(t+2); counted vmcnt at tail ----
#pragma unroll
    for (int ff = 0; ff < 4; ++ff) af[ff] = *(const bf16x8*)(Ab + (4 + ff) * 1024 + aRd);
    if (t + 2 < NT) STAGE_B(t + 2);
    asm volatile("s_barrier" ::: "memory");
    asm volatile("s_waitcnt lgkmcnt(0)" ::: "memory");
    PHASE_MFMA(4);
    if (t < NT - 2) { asm volatile("s_waitcnt vmcnt(2)" ::: "memory"); }
    else if (t == NT - 2) { asm volatile("s_waitcnt vmcnt(0)" ::: "memory"); }
    asm volatile("s_barrier" ::: "memory");
  }

  // ---------------- epilogue ----------------
  // C/D layout: col = lane&15 (d), row = (lane>>4)*4 + reg (batch)
  const int d = n0 + wn * 16 + l15;
  float bsv[NSEG], thv[NSEG];
#pragma unroll
  for (int s = 0; s < NSEG; ++s) {
    bsv[s] = b_seg[s * N_DIM + d];
    thv[s] = thr[s * N_DIM + d];
  }
#pragma unroll
  for (int f = 0; f < 8; ++f) {
#pragma unroll
    for (int r = 0; r < 4; ++r) {
      const int brow = m0 + wm * 128 + f * 16 + kg * 4 + r;
      const float4 g = *(const float4*)(gates + (size_t)brow * 4);
      const float gv[NSEG] = {g.x, g.y, g.z, g.w};
      float sum = 0.f, prod = 1.f;
#pragma unroll
      for (int s = 0; s < NSEG; ++s) {
        const float seg = acc[s][f][r] + bsv[s];
        const float pl = 1.f / (1.f + __expf(-5.f * (seg - thv[s])));
        const float st = seg * pl * gv[s];
        sum += st;
        prod *= st;
      }
      const float gm = sqrtf(sqrtf(fabsf(prod)));   // |prod|^(1/4)
      out[(size_t)brow * N_DIM + d] = sum + 0.1f * (prod < 0.f ? -gm : gm);
    }
  }
#undef STAGE_A
#undef STAGE_B
#undef PHASE_MFMA
#undef MFMA16
}

extern "C" void kernel_launch(void* const* d_in, const int* in_sizes, int n_in,
                              void* d_out, int out_size, void* d_ws, size_t ws_size,
                              hipStream_t stream) {
  const float* x      = (const float*)d_in[0];
  const float* W_seg  = (const float*)d_in[1];
  const float* b_seg  = (const float*)d_in[2];
  const float* thr    = (const float*)d_in[3];
  const float* W_gate = (const float*)d_in[4];
  const float* b_gate = (const float*)d_in[5];
  float* out = (float*)d_out;

  // workspace layout: x_bf16 (32MB) | W_bf16 (32MB) | gates (128KB)
  unsigned short* xb = (unsigned short*)d_ws;
  unsigned short* wb = xb + (size_t)B_DIM * K_DIM;
  float* gates = (float*)(wb + (size_t)NSEG * N_DIM * K_DIM);

  xconv_gates_kernel<<<B_DIM, 256, 0, stream>>>(x, W_gate, b_gate, xb, gates);
  convert_kernel<<<2048, 256, 0, stream>>>(W_seg, wb, NSEG * N_DIM * K_DIM / 8);

  dim3 grid(1024);
  seg_gemm_kernel<<<grid, 512, 0, stream>>>(xb, wb, b_seg, thr, gates, out);
}

// Round 5
// 319.781 us; speedup vs baseline: 6.5994x; 6.5994x over previous
//
#include <hip/hip_runtime.h>
#include <hip/hip_bf16.h>
#include <stdint.h>

#define B_DIM 8192
#define K_DIM 2048
#define N_DIM 2048
#define NSEG 4
#define NT (K_DIM / 64)   // 32 K-tiles of BK=64

typedef short bf16x8 __attribute__((ext_vector_type(8)));   // 8 bf16 (4 VGPRs)
typedef float f32x4 __attribute__((ext_vector_type(4)));
typedef unsigned short ushort8v __attribute__((ext_vector_type(8)));

typedef const __attribute__((address_space(1))) void* gas_ptr;
typedef __attribute__((address_space(3))) void* lds_ptr;

__device__ __forceinline__ unsigned short f2bf(float f) {
  uint32_t u = __float_as_uint(f);
  u += 0x7FFFu + ((u >> 16) & 1u);   // round-to-nearest-even
  return (unsigned short)(u >> 16);
}

// ---------------- W: f32 -> bf16 conversion, 8 elems/thread ----------------
__global__ __launch_bounds__(256)
void convert_kernel(const float* __restrict__ in, unsigned short* __restrict__ out, int n8) {
  int i = blockIdx.x * blockDim.x + threadIdx.x;
  const int stride = gridDim.x * blockDim.x;
  for (; i < n8; i += stride) {
    const float4* p = (const float4*)(in + (size_t)i * 8);
    float4 v0 = p[0];
    float4 v1 = p[1];
    ushort8v r;
    r[0] = f2bf(v0.x); r[1] = f2bf(v0.y); r[2] = f2bf(v0.z); r[3] = f2bf(v0.w);
    r[4] = f2bf(v1.x); r[5] = f2bf(v1.y); r[6] = f2bf(v1.z); r[7] = f2bf(v1.w);
    *(ushort8v*)(out + (size_t)i * 8) = r;
  }
}

// ------ fused: x f32 -> bf16 convert + gates = sigmoid(x @ Wg^T + bg) ------
__global__ __launch_bounds__(256)
void xconv_gates_kernel(const float* __restrict__ x, const float* __restrict__ Wg,
                        const float* __restrict__ bg,
                        unsigned short* __restrict__ xb, float* __restrict__ gates) {
  const int b = blockIdx.x;
  const int tid = threadIdx.x;
  const size_t base = (size_t)b * K_DIM + tid * 8;
  const float4 v0 = *(const float4*)(x + base);
  const float4 v1 = *(const float4*)(x + base + 4);
  ushort8v r;
  r[0] = f2bf(v0.x); r[1] = f2bf(v0.y); r[2] = f2bf(v0.z); r[3] = f2bf(v0.w);
  r[4] = f2bf(v1.x); r[5] = f2bf(v1.y); r[6] = f2bf(v1.z); r[7] = f2bf(v1.w);
  *(ushort8v*)(xb + base) = r;

  float a[4];
#pragma unroll
  for (int s = 0; s < 4; ++s) {
    const float4 w0 = *(const float4*)(Wg + (size_t)s * K_DIM + tid * 8);
    const float4 w1 = *(const float4*)(Wg + (size_t)s * K_DIM + tid * 8 + 4);
    a[s] = v0.x * w0.x + v0.y * w0.y + v0.z * w0.z + v0.w * w0.w
         + v1.x * w1.x + v1.y * w1.y + v1.z * w1.z + v1.w * w1.w;
  }
#pragma unroll
  for (int off = 1; off < 64; off <<= 1) {
#pragma unroll
    for (int s = 0; s < 4; ++s) a[s] += __shfl_xor(a[s], off);
  }
  __shared__ float red[4][4];
  const int wv = tid >> 6;
  if ((tid & 63) == 0) {
#pragma unroll
    for (int s = 0; s < 4; ++s) red[wv][s] = a[s];
  }
  __syncthreads();
  if (tid < 4) {
    float v = red[0][tid] + red[1][tid] + red[2][tid] + red[3][tid] + bg[tid];
    gates[(size_t)b * 4 + tid] = 1.f / (1.f + __expf(-v));
  }
}

// ------------- fused 4-segment GEMM, 16x16x32 MFMA, free-run schedule -------
// Geometry identical to R2 (the 294us/42% best): block = 256 rows x 64 d x
// 4 segs, 8 waves = 2M x 4N, per-wave 128x16x4segs, acc[4][8] f32x4.
// NEW: 1 barrier + 1 counted vmcnt per K-tile (was 8+8). Waves free-run
// within a tile; compiler inserts fine-grained lgkmcnt; cross-wave MFMA/LDS
// overlap replaces lockstep phase alternation.
// LDS 160 KiB: A double-buffered 2x32K (staged 1 tile ahead, parity^1),
// B TRIPLE-buffered 3x32K (staged 2 ahead; target buf held B(t-1), dead
// since the t-1 barrier). vmcnt: issue A(t+1) early, B(t+2) mid; at tile end
// outstanding = [B(t+1),A(t+1),B(t+2)] = 12 -> vmcnt(4) leaves B(t+2) flying.
// vmcnt(0) only at t==NT-2.
__global__ __launch_bounds__(512, 2)
void seg_gemm_kernel(const unsigned short* __restrict__ Xb,
                     const unsigned short* __restrict__ Wb,
                     const float* __restrict__ b_seg,
                     const float* __restrict__ thr,
                     const float* __restrict__ gates,
                     float* __restrict__ out) {
  extern __shared__ __align__(128) char smem[];   // 163840 bytes

  const int tid = threadIdx.x;
  const int lane = tid & 63;
  const int wid = tid >> 6;
  const int wm = wid >> 2;        // 0..1 (m half)
  const int wn = wid & 3;         // 0..3 (d quarter)

  // bijective XCD swizzle: 1024 blocks, 8 XCDs, 128 per XCD
  const int id = blockIdx.x;
  const int swz = (id & 7) * 128 + (id >> 3);
  const int m0 = (swz >> 5) * 256;
  const int n0 = (swz & 31) * 64;

  // ---- staging constants (verified zero-conflict, R2) ----
  const int row_st = ((tid >> 7) << 4) + ((tid >> 2) & 15);          // + j*64
  const int kb_st  = (((tid >> 6) & 1) << 6) + ((((tid & 3) << 4)) ^ (((tid >> 5) & 1) << 5));
  const int ke_st  = kb_st >> 1;
  const int ldsd   = tid * 16;

  // ---- read constants (verified zero-conflict, R2) ----
  const int l15 = lane & 15;
  const int kg  = lane >> 4;       // 0..3
  const int aRd = l15 * 64 + ((kg * 16) ^ ((l15 & 8) << 2));
  const int wnB = wn * 2048;

  f32x4 acc[NSEG][8];
#pragma unroll
  for (int s = 0; s < NSEG; ++s)
#pragma unroll
    for (int f = 0; f < 8; ++f) acc[s][f] = (f32x4){0.f, 0.f, 0.f, 0.f};

#define STAGE_A(t_, h_) do { int buf_ = (t_) & 1;                                   \
    const unsigned short* s0_ = Xb + (size_t)(m0 + (h_) * 128 + row_st) * K_DIM + (t_) * 64 + ke_st; \
    __builtin_amdgcn_global_load_lds((gas_ptr)s0_, (lds_ptr)(smem + buf_ * 32768 + (h_) * 16384 + ldsd), 16, 0, 0); \
    const unsigned short* s1_ = Xb + (size_t)(m0 + (h_) * 128 + row_st + 64) * K_DIM + (t_) * 64 + ke_st; \
    __builtin_amdgcn_global_load_lds((gas_ptr)s1_, (lds_ptr)(smem + buf_ * 32768 + (h_) * 16384 + ldsd + 8192), 16, 0, 0); \
  } while (0)

#define STAGE_B(t_, h_, bb_) do {                                                   \
    int e0_ = (h_) * 128 + row_st;                                                  \
    const unsigned short* s0_ = Wb + (size_t)(e0_ >> 6) * (N_DIM * K_DIM) + (size_t)(n0 + (e0_ & 63)) * K_DIM + (t_) * 64 + ke_st; \
    __builtin_amdgcn_global_load_lds((gas_ptr)s0_, (lds_ptr)(smem + 65536 + (bb_) * 32768 + (h_) * 16384 + ldsd), 16, 0, 0); \
    int e1_ = e0_ + 64;                                                             \
    const unsigned short* s1_ = Wb + (size_t)(e1_ >> 6) * (N_DIM * K_DIM) + (size_t)(n0 + (e1_ & 63)) * K_DIM + (t_) * 64 + ke_st; \
    __builtin_amdgcn_global_load_lds((gas_ptr)s1_, (lds_ptr)(smem + 65536 + (bb_) * 32768 + (h_) * 16384 + ldsd + 8192), 16, 0, 0); \
  } while (0)

#define MFMA16(a_, b_, c_) __builtin_amdgcn_mfma_f32_16x16x32_bf16(a_, b_, c_, 0, 0, 0)

  // ---- prologue: A(0), B(0)->buf0, B(1)->buf1; keep B(1) in flight ----
  STAGE_A(0, 0); STAGE_A(0, 1);
  STAGE_B(0, 0, 0); STAGE_B(0, 1, 0);
  STAGE_B(1, 0, 1); STAGE_B(1, 1, 1);
  asm volatile("s_waitcnt vmcnt(4)" ::: "memory");
  asm volatile("s_barrier" ::: "memory");

  int bc = 0, bs = 2;   // current / stage-target B buffer (mod 3)
  for (int t = 0; t < NT; ++t) {
    const char* Ab = smem + (t & 1) * 32768 + wm * 16384;
    const char* Bb = smem + 65536 + bc * 32768;

    // issue A(t+1) first (oldest in vmcnt FIFO after B(t+1))
    if (t + 1 < NT) { STAGE_A(t + 1, 0); STAGE_A(t + 1, 1); }

    // B fragments for tile t (held across both clusters)
    bf16x8 bfr[NSEG][2];
#pragma unroll
    for (int s = 0; s < NSEG; ++s) {
      const char* bp = Bb + (s >> 1) * 16384 + (s & 1) * 8192 + wnB + aRd;
      bfr[s][0] = *(const bf16x8*)(bp);
      bfr[s][1] = *(const bf16x8*)(bp + 1024);
    }

    // ---- cluster 1: m-frags 0..3 ----
    {
      bf16x8 af[4][2];
#pragma unroll
      for (int f = 0; f < 4; ++f) {
        af[f][0] = *(const bf16x8*)(Ab + f * 2048 + aRd);
        af[f][1] = *(const bf16x8*)(Ab + f * 2048 + 1024 + aRd);
      }
      __builtin_amdgcn_s_setprio(1);
#pragma unroll
      for (int f = 0; f < 4; ++f) {
#pragma unroll
        for (int s = 0; s < NSEG; ++s)
          acc[s][f] = MFMA16(af[f][0], bfr[s][0], acc[s][f]);
#pragma unroll
        for (int s = 0; s < NSEG; ++s)
          acc[s][f] = MFMA16(af[f][1], bfr[s][1], acc[s][f]);
      }
      __builtin_amdgcn_s_setprio(0);
    }

    // issue B(t+2) into the dead third buffer
    if (t + 2 < NT) { STAGE_B(t + 2, 0, bs); STAGE_B(t + 2, 1, bs); }

    // ---- cluster 2: m-frags 4..7 ----
    {
      bf16x8 af[4][2];
#pragma unroll
      for (int f = 0; f < 4; ++f) {
        af[f][0] = *(const bf16x8*)(Ab + (4 + f) * 2048 + aRd);
        af[f][1] = *(const bf16x8*)(Ab + (4 + f) * 2048 + 1024 + aRd);
      }
      __builtin_amdgcn_s_setprio(1);
#pragma unroll
      for (int f = 0; f < 4; ++f) {
#pragma unroll
        for (int s = 0; s < NSEG; ++s)
          acc[s][4 + f] = MFMA16(af[f][0], bfr[s][0], acc[s][4 + f]);
#pragma unroll
        for (int s = 0; s < NSEG; ++s)
          acc[s][4 + f] = MFMA16(af[f][1], bfr[s][1], acc[s][4 + f]);
      }
      __builtin_amdgcn_s_setprio(0);
    }

    // ---- tile tail: counted vmcnt + single barrier ----
    if (t < NT - 2)      { asm volatile("s_waitcnt vmcnt(4)" ::: "memory"); }
    else if (t == NT - 2){ asm volatile("s_waitcnt vmcnt(0)" ::: "memory"); }
    asm volatile("s_barrier" ::: "memory");

    bc = (bc == 2) ? 0 : bc + 1;
    bs = (bs == 2) ? 0 : bs + 1;
  }

  // ---------------- epilogue ----------------
  // C/D layout: col = lane&15 (d), row = (lane>>4)*4 + reg (batch)
  const int d = n0 + wn * 16 + l15;
  float bsv[NSEG], thv[NSEG];
#pragma unroll
  for (int s = 0; s < NSEG; ++s) {
    bsv[s] = b_seg[s * N_DIM + d];
    thv[s] = thr[s * N_DIM + d];
  }
#pragma unroll
  for (int f = 0; f < 8; ++f) {
#pragma unroll
    for (int r = 0; r < 4; ++r) {
      const int brow = m0 + wm * 128 + f * 16 + kg * 4 + r;
      const float4 g = *(const float4*)(gates + (size_t)brow * 4);
      const float gv[NSEG] = {g.x, g.y, g.z, g.w};
      float sum = 0.f, prod = 1.f;
#pragma unroll
      for (int s = 0; s < NSEG; ++s) {
        const float seg = acc[s][f][r] + bsv[s];
        const float pl = 1.f / (1.f + __expf(-5.f * (seg - thv[s])));
        const float st = seg * pl * gv[s];
        sum += st;
        prod *= st;
      }
      const float gm = sqrtf(sqrtf(fabsf(prod)));   // |prod|^(1/4)
      out[(size_t)brow * N_DIM + d] = sum + 0.1f * (prod < 0.f ? -gm : gm);
    }
  }
#undef STAGE_A
#undef STAGE_B
#undef MFMA16
}

extern "C" void kernel_launch(void* const* d_in, const int* in_sizes, int n_in,
                              void* d_out, int out_size, void* d_ws, size_t ws_size,
                              hipStream_t stream) {
  const float* x      = (const float*)d_in[0];
  const float* W_seg  = (const float*)d_in[1];
  const float* b_seg  = (const float*)d_in[2];
  const float* thr    = (const float*)d_in[3];
  const float* W_gate = (const float*)d_in[4];
  const float* b_gate = (const float*)d_in[5];
  float* out = (float*)d_out;

  // workspace layout: x_bf16 (32MB) | W_bf16 (32MB) | gates (128KB)
  unsigned short* xb = (unsigned short*)d_ws;
  unsigned short* wb = xb + (size_t)B_DIM * K_DIM;
  float* gates = (float*)(wb + (size_t)NSEG * N_DIM * K_DIM);

  xconv_gates_kernel<<<B_DIM, 256, 0, stream>>>(x, W_gate, b_gate, xb, gates);
  convert_kernel<<<2048, 256, 0, stream>>>(W_seg, wb, NSEG * N_DIM * K_DIM / 8);

  hipFuncSetAttribute((const void*)seg_gemm_kernel,
                      hipFuncAttributeMaxDynamicSharedMemorySize, 163840);
  seg_gemm_kernel<<<1024, 512, 163840, stream>>>(xb, wb, b_seg, thr, gates, out);
}